// Round 29
// baseline (142.307 us; speedup 1.0000x reference)
//
#include <hip/hip_runtime.h>
#include <math.h>

// Model_6150393168181 — bf16-MFMA pipeline, 3 launches.
//   prep_all: weight conversions (SBp/WL/WR/WRp)
//   mega4:    block 0 = ENTIRE chain (4 layers + cl4b) in ONE block — only
//             __syncthreads, no cross-block fences/atomics (round-28 lesson: the
//             agent-scope release/acquire chain sync cost ~30+ µs of L2 writeback).
//             blocks 1..8 prep_mb, 9..518 sage (barrier-free, per-wave 12K LDS).
//             LDS 49664 -> 3 blocks/CU -> all 519 blocks resident in one round.
//   attn:     Z-route attention
// Math: out[b] = f @ Z / sqrt(128), Z = sum_w MB_w^T (f^T SB_w^T);
//   MB_w[e][d] = sum_o' ksa[w,o',e] qsa[w,o',d];  f = rms(relu(SAGE4(rms(flows))));
//   SAGE agg (rows 0..127): corr_l = L @ (s.X_l @ wl_l^T), L[n][i]=(i<n)/max(n,1).
// Chain X between layers: ROW-major bf16 in global (XT1/2/3) -> A-frags are 16B
// vector loads; within-block RAW via same-XCD L2 (syncthreads drains vmcnt; L1 is
// write-no-allocate and lines are never read-before-write within a launch).

typedef __attribute__((ext_vector_type(8))) short bf16x8;
typedef __attribute__((ext_vector_type(4))) float f32x4;

__device__ inline ushort f2b(float x) {
  unsigned u = __builtin_bit_cast(unsigned, x);
  unsigned r = (u + 0x7fffu + ((u >> 16) & 1u)) >> 16;
  return (ushort)r;
}
__device__ inline int ftswz(int e) { return ((e & 7) ^ ((e >> 3) & 15)) << 4; }
__device__ inline int cAddrRow(int rl) { return (rl < 8) ? rl * 512 : 8192 + (rl - 8) * 512; }

// ---------------- prep: SBp + WL/WR + WRp ----------------
__global__ __launch_bounds__(256) void prep_all_k(
    const float* __restrict__ s2w,
    const float* __restrict__ wl1, const float* __restrict__ wl2,
    const float* __restrict__ wl3, const float* __restrict__ wl4,
    const float* __restrict__ wr1, const float* __restrict__ wr2,
    const float* __restrict__ wr3, const float* __restrict__ wr4,
    ushort* __restrict__ SBp, ushort* __restrict__ WL, ushort* __restrict__ WR,
    ushort* __restrict__ WRp) {
  int i = blockIdx.x * 256 + threadIdx.x;
  if (i < 131072) {
    int w = i >> 14, p = (i >> 7) & 127, m = i & 127;
    int sidx = ((((w * 2 + (p >> 6)) * 4 + ((p >> 4) & 3)) * 4 + (m >> 5)) * 64 +
                ((m >> 3) & 3) * 16 + (p & 15)) * 8 + (m & 7);
    SBp[sidx] = f2b(s2w[p * 1024 + m * 8 + w]);
    return;
  }
  i -= 131072;
  if (i < 98304) {
    float v, u;
    int base, K, col, k;
    if (i < 16384)      { v = wl1[i];         u = wr1[i];         base = 0;     K = 128; col = i >> 7;            k = i & 127; }
    else if (i < 49152) { int j = i - 16384;  v = wl2[j]; u = wr2[j]; base = 16384; K = 128; col = j >> 7;       k = j & 127; }
    else if (i < 81920) { int j = i - 49152;  v = wl3[j]; u = wr3[j]; base = 49152; K = 256; col = j >> 8;       k = j & 255; }
    else                { int j = i - 81920;  v = wl4[j]; u = wr4[j]; base = 81920; K = 128; col = j >> 7;       k = j & 127; }
    WL[i] = f2b(v);
    ushort ub = f2b(u);
    WR[i] = ub;
    int pidx = base + (((col >> 4) * (K / 32) + (k >> 5)) * 64 +
                       ((k >> 3) & 3) * 16 + (col & 15)) * 8 + (k & 7);
    WRp[pidx] = ub;
  }
}

// ---------------- single-block chain layer ----------------
// MODE 0: input = flows f32 (rms on the fly). MODE 1: input XRsrc bf16 row-major,
// output XRdst bf16 row-major. MODE 2: like 1 but output YT4 f32 (relu'd) + relu-ssq.
template <int K, int N, int MODE>
__device__ void chainS_dev(char* C0T, float* sArr, float* sSS,
                           const float* __restrict__ flows,
                           const ushort* __restrict__ XRsrc,
                           const ushort* __restrict__ Wl, const ushort* __restrict__ Wr,
                           const float* __restrict__ bias,
                           ushort* __restrict__ XRdst, float* __restrict__ YTdst) {
  const int tid = threadIdx.x;
  const int lane = tid & 63, wv = tid >> 6, lr = lane & 15, lg = lane >> 4;
  constexpr int NF = K / 32;
  constexpr int NCB = N / 16;

  __syncthreads();  // entry: prev layer's XR stores + sSS visible

  bf16x8 a[2][NF];
  #pragma unroll
  for (int mt = 0; mt < 2; ++mt) {
    int R = wv * 32 + mt * 16 + lr;
    if (MODE == 0) {
      float ssq = 0.f;
      #pragma unroll
      for (int ks = 0; ks < NF; ++ks) {
        const float4 v0 = *reinterpret_cast<const float4*>(flows + (size_t)R * K + ks * 32 + lg * 8);
        const float4 v1 = *reinterpret_cast<const float4*>(flows + (size_t)R * K + ks * 32 + lg * 8 + 4);
        ssq += v0.x * v0.x + v0.y * v0.y + v0.z * v0.z + v0.w * v0.w;
        ssq += v1.x * v1.x + v1.y * v1.y + v1.z * v1.z + v1.w * v1.w;
        union { ushort us[8]; bf16x8 v; } u;
        u.us[0] = f2b(v0.x); u.us[1] = f2b(v0.y); u.us[2] = f2b(v0.z); u.us[3] = f2b(v0.w);
        u.us[4] = f2b(v1.x); u.us[5] = f2b(v1.y); u.us[6] = f2b(v1.z); u.us[7] = f2b(v1.w);
        a[mt][ks] = u.v;
      }
      ssq += __shfl_xor(ssq, 16);
      ssq += __shfl_xor(ssq, 32);
      if (lg == 0) sArr[R] = rsqrtf(ssq * (1.0f / 128.0f));
    } else {
      #pragma unroll
      for (int ks = 0; ks < NF; ++ks)
        a[mt][ks] = *reinterpret_cast<const bf16x8*>(XRsrc + (size_t)R * K + ks * 32 + lg * 8);
    }
  }
  if (MODE != 0) {
    if (tid < 128) sArr[tid] = 1.0f / fmaxf(sqrtf(sSS[tid]), 1e-12f);
  }
  __syncthreads();  // sArr ready

  float sr[2][4];
  #pragma unroll
  for (int mt = 0; mt < 2; ++mt)
    #pragma unroll
    for (int rr = 0; rr < 4; ++rr)
      sr[mt][rr] = sArr[wv * 32 + mt * 16 + 4 * lg + rr];

  // triangular L fragments (held per layer)
  bf16x8 aL[2][4];
  #pragma unroll
  for (int mt = 0; mt < 2; ++mt) {
    int rowL = wv * 32 + mt * 16 + lr;
    ushort iv = f2b(1.0f / (float)(rowL > 1 ? rowL : 1));
    #pragma unroll
    for (int ks = 0; ks < 4; ++ks)
      #pragma unroll
      for (int j = 0; j < 8; ++j) {
        int k = ks * 32 + lg * 8 + j;
        aL[mt][ks][j] = (short)((k < rowL) ? iv : 0);
      }
  }

  float ssqo[2][4] = {{0.f, 0.f, 0.f, 0.f}, {0.f, 0.f, 0.f, 0.f}};

  constexpr int NCH = (NCB + 7) / 8;
  #pragma unroll
  for (int ch = 0; ch < NCH; ++ch) {
    // phase 1: acc1 = s.X @ Wl^T -> C0T slices (8 x 4KB)
    #pragma unroll
    for (int cb8 = 0; cb8 < 8; ++cb8) {
      int cb = ch * 8 + cb8;
      int cG = cb * 16 + lr;
      f32x4 acc[2] = {{0.f, 0.f, 0.f, 0.f}, {0.f, 0.f, 0.f, 0.f}};
      #pragma unroll
      for (int ks = 0; ks < NF; ++ks) {
        bf16x8 bw = *reinterpret_cast<const bf16x8*>(Wl + (size_t)cG * K + ks * 32 + lg * 8);
        acc[0] = __builtin_amdgcn_mfma_f32_16x16x32_bf16(a[0][ks], bw, acc[0], 0, 0, 0);
        acc[1] = __builtin_amdgcn_mfma_f32_16x16x32_bf16(a[1][ks], bw, acc[1], 0, 0, 0);
      }
      #pragma unroll
      for (int mt = 0; mt < 2; ++mt) {
        int m0 = wv * 32 + mt * 16 + lg * 4;
        uint2 pk;
        pk.x = (unsigned)f2b(acc[mt][0] * sr[mt][0]) | ((unsigned)f2b(acc[mt][1] * sr[mt][1]) << 16);
        pk.y = (unsigned)f2b(acc[mt][2] * sr[mt][2]) | ((unsigned)f2b(acc[mt][3] * sr[mt][3]) << 16);
        *reinterpret_cast<uint2*>(C0T + cb8 * 4096 + lr * 256 + ((2 * m0) ^ ((lr & 7) << 4))) = pk;
      }
    }
    __syncthreads();
    // phase 2: acc2 = s.X @ Wr^T ; cacc = L @ C0 ; epilogue
    #pragma unroll
    for (int cb8 = 0; cb8 < 8; ++cb8) {
      int cb = ch * 8 + cb8;
      int cG = cb * 16 + lr;
      f32x4 acc[2] = {{0.f, 0.f, 0.f, 0.f}, {0.f, 0.f, 0.f, 0.f}};
      #pragma unroll
      for (int ks = 0; ks < NF; ++ks) {
        bf16x8 bw = *reinterpret_cast<const bf16x8*>(Wr + (size_t)cG * K + ks * 32 + lg * 8);
        acc[0] = __builtin_amdgcn_mfma_f32_16x16x32_bf16(a[0][ks], bw, acc[0], 0, 0, 0);
        acc[1] = __builtin_amdgcn_mfma_f32_16x16x32_bf16(a[1][ks], bw, acc[1], 0, 0, 0);
      }
      bf16x8 bc[4];
      #pragma unroll
      for (int ks = 0; ks < 4; ++ks)
        bc[ks] = *reinterpret_cast<const bf16x8*>(
            C0T + cb8 * 4096 + lr * 256 + ((ks * 64 + lg * 16) ^ ((lr & 7) << 4)));
      float bb = bias[cG];
      #pragma unroll
      for (int mt = 0; mt < 2; ++mt) {
        f32x4 cacc = {0.f, 0.f, 0.f, 0.f};
        #pragma unroll
        for (int ks = 0; ks < 4; ++ks)
          cacc = __builtin_amdgcn_mfma_f32_16x16x32_bf16(aL[mt][ks], bc[ks], cacc, 0, 0, 0);
        int m0 = wv * 32 + mt * 16 + lg * 4;
        if (MODE < 2) {
          #pragma unroll
          for (int rr = 0; rr < 4; ++rr) {
            float y = acc[mt][rr] * sr[mt][rr] + bb + cacc[rr];
            XRdst[(size_t)(m0 + rr) * N + cG] = f2b(y);
            ssqo[mt][rr] += y * y;
          }
        } else {
          float4 vv;
          vv.x = fmaxf(acc[mt][0] * sr[mt][0] + bb + cacc[0], 0.f);
          vv.y = fmaxf(acc[mt][1] * sr[mt][1] + bb + cacc[1], 0.f);
          vv.z = fmaxf(acc[mt][2] * sr[mt][2] + bb + cacc[2], 0.f);
          vv.w = fmaxf(acc[mt][3] * sr[mt][3] + bb + cacc[3], 0.f);
          *reinterpret_cast<float4*>(&YTdst[(size_t)cG * 128 + m0]) = vv;
          ssqo[mt][0] += vv.x * vv.x; ssqo[mt][1] += vv.y * vv.y;
          ssqo[mt][2] += vv.z * vv.z; ssqo[mt][3] += vv.w * vv.w;
        }
      }
    }
    __syncthreads();  // C0T reusable / stores ordered before next phase1
  }

  // output row ssq -> sSS
  #pragma unroll
  for (int mt = 0; mt < 2; ++mt)
    #pragma unroll
    for (int rr = 0; rr < 4; ++rr) {
      float ss = ssqo[mt][rr];
      ss += __shfl_xor(ss, 1); ss += __shfl_xor(ss, 2);
      ss += __shfl_xor(ss, 4); ss += __shfl_xor(ss, 8);
      if (lr == 0) sSS[wv * 32 + mt * 16 + 4 * lg + rr] = ss;
    }
}

// ---------------- sage (barrier-free, per-wave 12K region) ----------------
__device__ inline void sage_stage(const float* __restrict__ flows, int blk,
                                  char* W, float* sArr, int wv, int lane) {
  int r2 = lane >> 5;
  int c4 = lane & 31;
  #pragma unroll
  for (int it = 0; it < 8; ++it) {
    int rl0 = it * 2;
    const float4 v = *reinterpret_cast<const float4*>(
        flows + ((size_t)blk * 64 + wv * 16 + rl0) * 128 + lane * 4);
    int rl = rl0 + r2;
    float ss = v.x * v.x + v.y * v.y + v.z * v.z + v.w * v.w;
    ss += __shfl_xor(ss, 16); ss += __shfl_xor(ss, 8);
    ss += __shfl_xor(ss, 4);  ss += __shfl_xor(ss, 2); ss += __shfl_xor(ss, 1);
    uint2 pk;
    pk.x = (unsigned)f2b(v.x) | ((unsigned)f2b(v.y) << 16);
    pk.y = (unsigned)f2b(v.z) | ((unsigned)f2b(v.w) << 16);
    *reinterpret_cast<uint2*>(W + rl * 256 + ((c4 * 8) ^ ((rl & 7) << 4))) = pk;
    if (c4 == 0) sArr[wv * 16 + rl] = rsqrtf(ss * (1.0f / 128.0f));
  }
}

template <int N, int DSTC>
__device__ inline void sage_l128(const char* src, char* dstW,
                                 const float* sP, float* sN,
                                 const ushort* __restrict__ Wrp,
                                 const float* __restrict__ bias,
                                 int wv, int lr, int lg, int l64) {
  bf16x8 a[4];
  float sr[4];
  #pragma unroll
  for (int ks = 0; ks < 4; ++ks)
    a[ks] = *reinterpret_cast<const bf16x8*>(src + lr * 256 + ((ks * 64 + lg * 16) ^ ((lr & 7) << 4)));
  #pragma unroll
  for (int rr = 0; rr < 4; ++rr) sr[rr] = sP[wv * 16 + 4 * lg + rr];
  float ssq[4] = {0.f, 0.f, 0.f, 0.f};
  #pragma unroll
  for (int nt = 0; nt < N / 16; ++nt) {
    int col = nt * 16 + lr;
    bf16x8 b[4];
    #pragma unroll
    for (int ks = 0; ks < 4; ++ks)
      b[ks] = *reinterpret_cast<const bf16x8*>(Wrp + (((size_t)nt * 4 + ks) * 64 + l64) * 8);
    f32x4 acc = {0.f, 0.f, 0.f, 0.f};
    #pragma unroll
    for (int ks = 0; ks < 4; ++ks)
      acc = __builtin_amdgcn_mfma_f32_16x16x32_bf16(a[ks], b[ks], acc, 0, 0, 0);
    float bb = bias[col];
    #pragma unroll
    for (int rr = 0; rr < 4; ++rr) {
      int rl = 4 * lg + rr;
      float y = acc[rr] * sr[rr] + bb;
      int rowbase = DSTC ? cAddrRow(rl) : rl * 256;
      *reinterpret_cast<ushort*>(dstW + rowbase + ((col * 2) ^ ((rl & 7) << 4))) = f2b(y);
      ssq[rr] += y * y;
    }
  }
  #pragma unroll
  for (int rr = 0; rr < 4; ++rr) {
    float ss = ssq[rr];
    ss += __shfl_xor(ss, 1); ss += __shfl_xor(ss, 2);
    ss += __shfl_xor(ss, 4); ss += __shfl_xor(ss, 8);
    if (lr == 0) sN[wv * 16 + 4 * lg + rr] = 1.0f / fmaxf(sqrtf(ss), 1e-12f);
  }
}

__device__ inline void sage_l3(const char* W, char* dstD,
                               const float* sP, float* sN,
                               const ushort* __restrict__ Wrp,
                               const float* __restrict__ bias,
                               int wv, int lr, int lg, int l64) {
  bf16x8 a[8];
  float sr[4];
  #pragma unroll
  for (int ks = 0; ks < 8; ++ks)
    a[ks] = *reinterpret_cast<const bf16x8*>(W + cAddrRow(lr) + ((ks * 64 + lg * 16) ^ ((lr & 7) << 4)));
  #pragma unroll
  for (int rr = 0; rr < 4; ++rr) sr[rr] = sP[wv * 16 + 4 * lg + rr];
  float ssq[4] = {0.f, 0.f, 0.f, 0.f};
  #pragma unroll
  for (int nt = 0; nt < 8; ++nt) {
    int col = nt * 16 + lr;
    f32x4 acc = {0.f, 0.f, 0.f, 0.f};
    #pragma unroll
    for (int ks = 0; ks < 8; ++ks) {
      bf16x8 b = *reinterpret_cast<const bf16x8*>(Wrp + (((size_t)nt * 8 + ks) * 64 + l64) * 8);
      acc = __builtin_amdgcn_mfma_f32_16x16x32_bf16(a[ks], b, acc, 0, 0, 0);
    }
    float bb = bias[col];
    #pragma unroll
    for (int rr = 0; rr < 4; ++rr) {
      int rl = 4 * lg + rr;
      float y = acc[rr] * sr[rr] + bb;
      *reinterpret_cast<ushort*>(dstD + rl * 256 + ((col * 2) ^ ((rl & 7) << 4))) = f2b(y);
      ssq[rr] += y * y;
    }
  }
  #pragma unroll
  for (int rr = 0; rr < 4; ++rr) {
    float ss = ssq[rr];
    ss += __shfl_xor(ss, 1); ss += __shfl_xor(ss, 2);
    ss += __shfl_xor(ss, 4); ss += __shfl_xor(ss, 8);
    if (lr == 0) sN[wv * 16 + 4 * lg + rr] = 1.0f / fmaxf(sqrtf(ss), 1e-12f);
  }
}

__device__ inline void sage_l4(const char* src, const float* sP,
                               const ushort* __restrict__ Wrp,
                               const float* __restrict__ bias,
                               int wv, int lr, int lg, int l64,
                               ushort* __restrict__ Fg, int blk) {
  bf16x8 a[4];
  float sr[4];
  #pragma unroll
  for (int ks = 0; ks < 4; ++ks)
    a[ks] = *reinterpret_cast<const bf16x8*>(src + lr * 256 + ((ks * 64 + lg * 16) ^ ((lr & 7) << 4)));
  #pragma unroll
  for (int rr = 0; rr < 4; ++rr) sr[rr] = sP[wv * 16 + 4 * lg + rr];
  float yreg[8][4];
  float ssq[4] = {0.f, 0.f, 0.f, 0.f};
  #pragma unroll
  for (int nt = 0; nt < 8; ++nt) {
    int col = nt * 16 + lr;
    bf16x8 b[4];
    #pragma unroll
    for (int ks = 0; ks < 4; ++ks)
      b[ks] = *reinterpret_cast<const bf16x8*>(Wrp + (((size_t)nt * 4 + ks) * 64 + l64) * 8);
    f32x4 acc = {0.f, 0.f, 0.f, 0.f};
    #pragma unroll
    for (int ks = 0; ks < 4; ++ks)
      acc = __builtin_amdgcn_mfma_f32_16x16x32_bf16(a[ks], b[ks], acc, 0, 0, 0);
    float bb = bias[col];
    #pragma unroll
    for (int rr = 0; rr < 4; ++rr) {
      float y = acc[rr] * sr[rr] + bb;
      yreg[nt][rr] = y;
      float v = fmaxf(y, 0.f);
      ssq[rr] += v * v;
    }
  }
  float sc[4];
  #pragma unroll
  for (int rr = 0; rr < 4; ++rr) {
    float ss = ssq[rr];
    ss += __shfl_xor(ss, 1); ss += __shfl_xor(ss, 2);
    ss += __shfl_xor(ss, 4); ss += __shfl_xor(ss, 8);
    sc[rr] = sqrtf(128.0f / fmaxf(ss, 1e-20f));
  }
  #pragma unroll
  for (int nt = 0; nt < 8; ++nt)
    #pragma unroll
    for (int rr = 0; rr < 4; ++rr) {
      int row = wv * 16 + 4 * lg + rr;
      Fg[((size_t)blk * 64 + row) * 128 + nt * 16 + lr] = f2b(fmaxf(yreg[nt][rr], 0.f) * sc[rr]);
    }
}

// ---------------- mega4: chain (0) + prep_mb (1..8) + sage (9..518) ----------------
__global__ __launch_bounds__(256, 2) void mega4_k(
    const float* __restrict__ flows,
    const float* __restrict__ qsa, const float* __restrict__ ksa,
    const ushort* __restrict__ WL, const ushort* __restrict__ WR,
    const ushort* __restrict__ WRp,
    const float* __restrict__ bl1, const float* __restrict__ bl2,
    const float* __restrict__ bl3, const float* __restrict__ bl4,
    ushort* __restrict__ Fg, ushort* __restrict__ MBT,
    ushort* __restrict__ XT1, ushort* __restrict__ XT2, ushort* __restrict__ XT3,
    float* __restrict__ YT4) {
  __shared__ char L[49664];
  const int bid = blockIdx.x;
  const int tid = threadIdx.x;
  const int lane = tid & 63, wv = tid >> 6, lr = lane & 15, lg = lane >> 4;

  if (bid == 0) {
    // ---- full chain, one block, LDS: C0T 32K | sArr 512 | sSS 512 ----
    char* C0T = L;
    float* sArr = (float*)(L + 32768);
    float* sSS = (float*)(L + 33280);
    chainS_dev<128, 128, 0>(C0T, sArr, sSS, flows, nullptr, WL + 0, WR + 0, bl1, XT1, nullptr);
    chainS_dev<128, 256, 1>(C0T, sArr, sSS, nullptr, XT1, WL + 16384, WR + 16384, bl2, XT2, nullptr);
    chainS_dev<256, 128, 1>(C0T, sArr, sSS, nullptr, XT2, WL + 49152, WR + 49152, bl3, XT3, nullptr);
    chainS_dev<128, 128, 2>(C0T, sArr, sSS, nullptr, XT3, WL + 81920, WR + 81920, bl4, nullptr, YT4);
    __syncthreads();  // YT4 + sSS visible
    // cl4b in-block: 2048 items, 8 iters
    #pragma unroll
    for (int i = 0; i < 8; ++i) {
      int t = i * 256 + tid;
      int r = t >> 4, cs = t & 15;
      float sc = sqrtf(128.0f / fmaxf(sSS[r], 1e-20f));
      ushort tmp[8];
      #pragma unroll
      for (int j = 0; j < 8; ++j) {
        int c = cs * 8 + j;
        tmp[j] = f2b(YT4[(size_t)c * 128 + r] * sc);
      }
      *reinterpret_cast<uint4*>(&Fg[(size_t)r * 128 + cs * 8]) = *reinterpret_cast<uint4*>(tmp);
    }
    return;
  }

  if (bid < 9) {
    // ---- prep_mb: QT in LDS; K-frags gathered from global ----
    char* QT = L;
    int w = bid - 1;
    const float* qw = qsa + (size_t)w * 16384;
    const float* kw = ksa + (size_t)w * 16384;
    for (int e = tid; e < 16384; e += 256) {
      int op = e >> 7, c = e & 127;
      int off = c * 256 + ((op * 2) ^ ((c & 7) << 4));
      *reinterpret_cast<ushort*>(QT + off) = f2b(qw[e]);
    }
    __syncthreads();
    #pragma unroll
    for (int rt = 0; rt < 2; ++rt) {
      int e = wv * 32 + rt * 16 + lr;
      bf16x8 a[4];
      #pragma unroll
      for (int ks = 0; ks < 4; ++ks) {
        union { ushort us[8]; bf16x8 v; } u;
        #pragma unroll
        for (int j = 0; j < 8; ++j)
          u.us[j] = f2b(kw[(size_t)(ks * 32 + lg * 8 + j) * 128 + e]);
        a[ks] = u.v;
      }
      #pragma unroll
      for (int ct = 0; ct < 8; ++ct) {
        int d = ct * 16 + lr;
        bf16x8 bq[4];
        #pragma unroll
        for (int ks = 0; ks < 4; ++ks)
          bq[ks] = *reinterpret_cast<const bf16x8*>(QT + d * 256 + ((ks * 64 + lg * 16) ^ ((d & 7) << 4)));
        f32x4 acc = {0.f, 0.f, 0.f, 0.f};
        #pragma unroll
        for (int ks = 0; ks < 4; ++ks)
          acc = __builtin_amdgcn_mfma_f32_16x16x32_bf16(a[ks], bq[ks], acc, 0, 0, 0);
        uint2 pk;
        pk.x = (unsigned)f2b(acc[0]) | ((unsigned)f2b(acc[1]) << 16);
        pk.y = (unsigned)f2b(acc[2]) | ((unsigned)f2b(acc[3]) << 16);
        size_t base = ((((size_t)ct * 8 + w) * 4 + wv) * 64 +
                       (size_t)(((rt * 2 + (lg >> 1)) & 3) * 16 + lr)) * 8 + (lg & 1) * 4;
        *reinterpret_cast<uint2*>(&MBT[base]) = pk;
      }
    }
    return;
  }

  // ---- sage path ----
  char* W = L + wv * 12288;
  float* sA = (float*)(L + 49152);
  float* sB = (float*)(L + 49408);
  const int l64 = lane;
  int blk = bid - 9 + 2;
  sage_stage(flows, blk, W, sA, wv, lane);
  asm volatile("" ::: "memory");
  sage_l128<128, 0>(W, W + 4096, sA, sB, WRp + 0,     bl1, wv, lr, lg, l64);
  asm volatile("" ::: "memory");
  sage_l128<256, 1>(W + 4096, W, sB, sA, WRp + 16384, bl2, wv, lr, lg, l64);
  asm volatile("" ::: "memory");
  sage_l3(W, W + 4096, sA, sB, WRp + 49152, bl3, wv, lr, lg, l64);
  asm volatile("" ::: "memory");
  sage_l4(W + 4096, sB, WRp + 81920, bl4, wv, lr, lg, l64, Fg, blk);
}

// ---------------- attn v6: 512 blocks x 512 thr, dbuf RT, coalesced SBp/MBT ----------------
__global__ __launch_bounds__(512, 4) void attn_fused(
    const ushort* __restrict__ F, const ushort* __restrict__ MBT,
    const ushort* __restrict__ SBp, float* __restrict__ Out) {
  __shared__ char FT[32768];
  __shared__ char RTb[32768];

  const int bq = blockIdx.x;
  const int b = bq >> 1, ph = bq & 1;
  const int tid = threadIdx.x;
  const int l = tid & 63, wv = tid >> 6;
  const int lr = l & 15, lg = l >> 4;

  const ushort* Fb = F + (size_t)b * 16384;

  #pragma unroll
  for (int it = 0; it < 4; ++it) {
    int idx = tid + it * 512;
    int m = idx >> 4, eg = idx & 15;
    uint4 v = *reinterpret_cast<const uint4*>(Fb + m * 128 + eg * 8);
    const ushort* pv = reinterpret_cast<const ushort*>(&v);
    #pragma unroll
    for (int j = 0; j < 8; ++j) {
      int e = eg * 8 + j;
      *reinterpret_cast<ushort*>(FT + e * 256 + ((m * 2) ^ ftswz(e))) = pv[j];
    }
  }

  bf16x8 fa[4];
  {
    int n = wv * 16 + lr;
    #pragma unroll
    for (int ks = 0; ks < 4; ++ks)
      fa[ks] = *reinterpret_cast<const bf16x8*>(Fb + n * 128 + ks * 32 + lg * 8);
  }
  __syncthreads();

  bf16x8 af[4];
  {
    int e = wv * 16 + lr;
    #pragma unroll
    for (int ks = 0; ks < 4; ++ks)
      af[ks] = *reinterpret_cast<const bf16x8*>(
          FT + e * 256 + ((ks * 64 + lg * 16) ^ ftswz(e)));
  }

  f32x4 zacc[4];
  #pragma unroll
  for (int pt = 0; pt < 4; ++pt) zacc[pt] = f32x4{0.f, 0.f, 0.f, 0.f};

  const int eb0 = 2 * (wv * 16 + lg * 4);

  auto Rphase = [&](int w, char* RT) {
    #pragma unroll
    for (int pt = 0; pt < 4; ++pt) {
      int p = pt * 16 + lr;
      bf16x8 bs[4];
      #pragma unroll
      for (int ks = 0; ks < 4; ++ks)
        bs[ks] = *reinterpret_cast<const bf16x8*>(
            SBp + ((((size_t)(w * 2 + ph) * 4 + pt) * 4 + ks) * 64 + l) * 8);
      f32x4 rr = {0.f, 0.f, 0.f, 0.f};
      #pragma unroll
      for (int ks = 0; ks < 4; ++ks)
        rr = __builtin_amdgcn_mfma_f32_16x16x32_bf16(af[ks], bs[ks], rr, 0, 0, 0);
      uint2 pk;
      pk.x = (unsigned)f2b(rr[0]) | ((unsigned)f2b(rr[1]) << 16);
      pk.y = (unsigned)f2b(rr[2]) | ((unsigned)f2b(rr[3]) << 16);
      *reinterpret_cast<uint2*>(RT + p * 256 + (eb0 ^ ((p & 7) << 4))) = pk;
    }
  };
  auto Zphase = [&](int w, const char* RT) {
    bf16x8 mf[4];
    #pragma unroll
    for (int ks = 0; ks < 4; ++ks)
      mf[ks] = *reinterpret_cast<const bf16x8*>(
          MBT + ((((size_t)wv * 8 + w) * 4 + ks) * 64 + l) * 8);
    #pragma unroll
    for (int pt = 0; pt < 4; ++pt) {
      int p = pt * 16 + lr;
      bf16x8 bg[4];
      #pragma unroll
      for (int ks = 0; ks < 4; ++ks)
        bg[ks] = *reinterpret_cast<const bf16x8*>(
            RT + p * 256 + ((ks * 64 + lg * 16) ^ ((p & 7) << 4)));
      #pragma unroll
      for (int ks = 0; ks < 4; ++ks)
        zacc[pt] = __builtin_amdgcn_mfma_f32_16x16x32_bf16(mf[ks], bg[ks], zacc[pt], 0, 0, 0);
    }
  };

  Rphase(0, RTb);
  __syncthreads();
  #pragma unroll
  for (int w = 0; w < 7; ++w) {
    Zphase(w, RTb + (w & 1) * 16384);
    Rphase(w + 1, RTb + ((w + 1) & 1) * 16384);
    __syncthreads();
  }
  Zphase(7, RTb + 16384);
  #pragma unroll
  for (int pt = 0; pt < 4; ++pt) {
    int p = pt * 16 + lr;
    uint2 pk;
    pk.x = (unsigned)f2b(zacc[pt][0]) | ((unsigned)f2b(zacc[pt][1]) << 16);
    pk.y = (unsigned)f2b(zacc[pt][2]) | ((unsigned)f2b(zacc[pt][3]) << 16);
    *reinterpret_cast<uint2*>(RTb + p * 256 + (eb0 ^ ((p & 7) << 4))) = pk;
  }
  __syncthreads();

  const float inv_scale = 0.08838834764831845f;
  float* ob = Out + (size_t)b * 16384 + ph * 64;
  #pragma unroll
  for (int pt = 0; pt < 4; ++pt) {
    int p = pt * 16 + lr;
    bf16x8 bz[4];
    #pragma unroll
    for (int ks = 0; ks < 4; ++ks)
      bz[ks] = *reinterpret_cast<const bf16x8*>(
          RTb + p * 256 + ((ks * 64 + lg * 16) ^ ((p & 7) << 4)));
    f32x4 oa = {0.f, 0.f, 0.f, 0.f};
    #pragma unroll
    for (int ks = 0; ks < 4; ++ks)
      oa = __builtin_amdgcn_mfma_f32_16x16x32_bf16(fa[ks], bz[ks], oa, 0, 0, 0);
    int n0 = wv * 16 + lg * 4;
    #pragma unroll
    for (int r = 0; r < 4; ++r)
      ob[(size_t)(n0 + r) * 128 + p] = oa[r] * inv_scale;
  }
}

extern "C" void kernel_launch(void* const* d_in, const int* in_sizes, int n_in,
                              void* d_out, int out_size, void* d_ws, size_t ws_size,
                              hipStream_t stream) {
  const float* flows = (const float*)d_in[0];
  const float* g1_wl = (const float*)d_in[10];
  const float* g1_bl = (const float*)d_in[11];
  const float* g1_wr = (const float*)d_in[12];
  const float* g2_wl = (const float*)d_in[13];
  const float* g2_bl = (const float*)d_in[14];
  const float* g2_wr = (const float*)d_in[15];
  const float* g3_wl = (const float*)d_in[16];
  const float* g3_bl = (const float*)d_in[17];
  const float* g3_wr = (const float*)d_in[18];
  const float* g4_wl = (const float*)d_in[19];
  const float* g4_bl = (const float*)d_in[20];
  const float* g4_wr = (const float*)d_in[21];
  const float* qsa   = (const float*)d_in[24];
  const float* ksa   = (const float*)d_in[25];
  const float* s2w   = (const float*)d_in[27];
  float* out = (float*)d_out;
  char* wsb  = (char*)d_ws;

  // workspace layout (bytes)
  ushort* FB16 = (ushort*)(wsb);                 // 32768*128 bf16 = 8388608
  ushort* SBp  = (ushort*)(wsb + 8388608);       // 131072 bf16 (permuted)
  ushort* WL   = (ushort*)(wsb + 8650752);       // 98304 bf16
  ushort* WR   = (ushort*)(wsb + 8847360);       // 98304 bf16
  ushort* MBT  = (ushort*)(wsb + 9043968);       // 131072 bf16 (permuted)
  ushort* XT1  = (ushort*)(wsb + 9306112);       // 128*128 bf16 (row-major)
  ushort* XT2  = (ushort*)(wsb + 9338880);       // 128*256 bf16 (row-major)
  ushort* XT3  = (ushort*)(wsb + 9404416);       // 128*128 bf16 (row-major)
  float*  YT4  = (float*)(wsb + 9437184);        // 128*128 f32 (col-major)
  ushort* WRp  = (ushort*)(wsb + 9504768);       // 98304 bf16 (permuted)

  prep_all_k<<<896, 256, 0, stream>>>(s2w,
                                      g1_wl, g2_wl, g3_wl, g4_wl,
                                      g1_wr, g2_wr, g3_wr, g4_wr,
                                      SBp, WL, WR, WRp);
  mega4_k<<<519, 256, 0, stream>>>(flows, qsa, ksa, WL, WR, WRp,
                                   g1_bl, g2_bl, g3_bl, g4_bl,
                                   FB16, MBT, XT1, XT2, XT3, YT4);
  attn_fused<<<512, 512, 0, stream>>>(FB16, MBT, SBp, out);
}

// Round 30
// 83.826 us; speedup vs baseline: 1.6976x; 1.6976x over previous
//
#include <hip/hip_runtime.h>
#include <math.h>

// Model_6150393168181 — bf16-MFMA pipeline, 3 launches.
//   prep_all: weight conversions (SBp/WL/WR/WRp) + SS/CTR zero
//   mega3:    blocks 0..15 chain (K-half staged, counter sync), 16..23 prep_mb,
//             24..533 sage (barrier-free, per-wave 12K LDS regions)
//   attn:     Z-route attention
// v12 sync rework (round-29/30 lesson): the old chain sync used ACQUIRE spins +
// __threadfence (agent scope) -> per-poll L2 invalidates + writebacks on all 8 XCDs,
// poisoning sage's weight caches chip-wide (~22 us of the 52 us mega time).
// Now: RELAXED polls (no cache ops); producers order stores with __threadfence_block
// (vmcnt drain only) + relaxed agent atomicAdd; ALL cross-block data (XT1/2/3, YT4,
// SS) moves via agent-scope relaxed atomic 64/32-bit loads/stores, which bypass the
// non-coherent per-XCD L2s entirely. No wbl2, no inv, bit-identical math.
// Math: out[b] = f @ Z / sqrt(128), Z = sum_w MB_w^T (f^T SB_w^T);
//   MB_w[e][d] = sum_o' ksa[w,o',e] qsa[w,o',d];  f = rms(relu(SAGE4(rms(flows))));
//   SAGE agg (rows 0..127): corr_l = L @ (s.X_l @ wl_l^T), L[n][i]=(i<n)/max(n,1).

typedef __attribute__((ext_vector_type(8))) short bf16x8;
typedef __attribute__((ext_vector_type(4))) float f32x4;

__device__ inline ushort f2b(float x) {
  unsigned u = __builtin_bit_cast(unsigned, x);
  unsigned r = (u + 0x7fffu + ((u >> 16) & 1u)) >> 16;
  return (ushort)r;
}
__device__ inline int ftswz(int e) { return ((e & 7) ^ ((e >> 3) & 15)) << 4; }
__device__ inline int cAddrRow(int rl) { return (rl < 8) ? rl * 512 : 8192 + (rl - 8) * 512; }

// ---- agent-scope bypass accessors (no cache maintenance; L2-incoherent-safe) ----
__device__ inline void st_byp64(void* p, unsigned long long v) {
  __hip_atomic_store((unsigned long long*)p, v, __ATOMIC_RELAXED, __HIP_MEMORY_SCOPE_AGENT);
}
__device__ inline unsigned long long ld_byp64(const void* p) {
  return __hip_atomic_load((unsigned long long*)p, __ATOMIC_RELAXED, __HIP_MEMORY_SCOPE_AGENT);
}
__device__ inline float ld_bypf(const float* p) {
  return __hip_atomic_load((float*)p, __ATOMIC_RELAXED, __HIP_MEMORY_SCOPE_AGENT);
}

__device__ inline void ctr_signal(unsigned* c) {
  __threadfence_block();   // vmcnt/lgkm drain, NO cache ops (bypass stores already coherent)
  __syncthreads();
  if (threadIdx.x == 0)
    __hip_atomic_fetch_add(c, 1u, __ATOMIC_RELAXED, __HIP_MEMORY_SCOPE_AGENT);
}
__device__ inline void ctr_wait(unsigned* c, unsigned tgt) {
  if (threadIdx.x == 0) {
    while (__hip_atomic_load(c, __ATOMIC_RELAXED, __HIP_MEMORY_SCOPE_AGENT) < tgt)
      __builtin_amdgcn_s_sleep(2);
  }
  __syncthreads();
}

// ---------------- prep: SBp + WL/WR + WRp + SS/CTR zero ----------------
__global__ __launch_bounds__(256) void prep_all_k(
    const float* __restrict__ s2w,
    const float* __restrict__ wl1, const float* __restrict__ wl2,
    const float* __restrict__ wl3, const float* __restrict__ wl4,
    const float* __restrict__ wr1, const float* __restrict__ wr2,
    const float* __restrict__ wr3, const float* __restrict__ wr4,
    ushort* __restrict__ SBp, ushort* __restrict__ WL, ushort* __restrict__ WR,
    ushort* __restrict__ WRp, float* __restrict__ SS, unsigned* __restrict__ CTR) {
  if (blockIdx.x == 0) {
    SS[threadIdx.x] = 0.f;
    SS[threadIdx.x + 256] = 0.f;
    if (threadIdx.x < 8) CTR[threadIdx.x] = 0u;
  }
  int i = blockIdx.x * 256 + threadIdx.x;
  if (i < 131072) {
    int w = i >> 14, p = (i >> 7) & 127, m = i & 127;
    int sidx = ((((w * 2 + (p >> 6)) * 4 + ((p >> 4) & 3)) * 4 + (m >> 5)) * 64 +
                ((m >> 3) & 3) * 16 + (p & 15)) * 8 + (m & 7);
    SBp[sidx] = f2b(s2w[p * 1024 + m * 8 + w]);
    return;
  }
  i -= 131072;
  if (i < 98304) {
    float v, u;
    int base, K, col, k;
    if (i < 16384)      { v = wl1[i];         u = wr1[i];         base = 0;     K = 128; col = i >> 7;            k = i & 127; }
    else if (i < 49152) { int j = i - 16384;  v = wl2[j]; u = wr2[j]; base = 16384; K = 128; col = j >> 7;       k = j & 127; }
    else if (i < 81920) { int j = i - 49152;  v = wl3[j]; u = wr3[j]; base = 49152; K = 256; col = j >> 8;       k = j & 255; }
    else                { int j = i - 81920;  v = wl4[j]; u = wr4[j]; base = 81920; K = 128; col = j >> 7;       k = j & 127; }
    WL[i] = f2b(v);
    ushort ub = f2b(u);
    WR[i] = ub;
    int pidx = base + (((col >> 4) * (K / 32) + (k >> 5)) * 64 +
                       ((k >> 3) & 3) * 16 + (col & 15)) * 8 + (k & 7);
    WRp[pidx] = ub;
  }
}

// ---------------- chain layer (16-col slice; K staged in 128-halves, acc in regs) ----------------
template <int K, int N, int MODE>
__device__ void chain_dev(char* XS, char* C0T, float* sArr,
                          const float* __restrict__ flows, const ushort* __restrict__ XTsrc,
                          const float* __restrict__ SSprev,
                          const ushort* __restrict__ Wl, const ushort* __restrict__ Wr,
                          const float* __restrict__ bias,
                          ushort* __restrict__ XTdst, float* __restrict__ YTdst,
                          float* __restrict__ SScur, int cbid) {
  const int tid = threadIdx.x;
  const int lane = tid & 63, wv = tid >> 6, lr = lane & 15, lg = lane >> 4;
  const int cG = cbid * 16 + lr;
  constexpr int NH = K / 128;

  float sr[2][4];
  f32x4 acc1[2] = {{0.f,0.f,0.f,0.f},{0.f,0.f,0.f,0.f}};
  f32x4 acc2[2] = {{0.f,0.f,0.f,0.f},{0.f,0.f,0.f,0.f}};

  #pragma unroll
  for (int h = 0; h < NH; ++h) {
    __syncthreads();
    if (MODE == 0) {
      #pragma unroll
      for (int it = 0; it < 16; ++it) {
        int idx = tid + it * 256;
        int row = idx >> 5, c4 = idx & 31;
        const float4 v = *reinterpret_cast<const float4*>(flows + (size_t)row * 128 + c4 * 4);
        float ss = v.x * v.x + v.y * v.y + v.z * v.z + v.w * v.w;
        ss += __shfl_xor(ss, 16); ss += __shfl_xor(ss, 8);
        ss += __shfl_xor(ss, 4);  ss += __shfl_xor(ss, 2); ss += __shfl_xor(ss, 1);
        *reinterpret_cast<ushort*>(XS + (c4 * 4 + 0) * 272 + row * 2) = f2b(v.x);
        *reinterpret_cast<ushort*>(XS + (c4 * 4 + 1) * 272 + row * 2) = f2b(v.y);
        *reinterpret_cast<ushort*>(XS + (c4 * 4 + 2) * 272 + row * 2) = f2b(v.z);
        *reinterpret_cast<ushort*>(XS + (c4 * 4 + 3) * 272 + row * 2) = f2b(v.w);
        if ((tid & 31) == 0) sArr[row] = rsqrtf(ss * (1.0f / 128.0f));
      }
    } else {
      for (int e = tid * 8; e < 16384; e += 2048) {
        unsigned long long v0 = ld_byp64(XTsrc + h * 16384 + e);
        unsigned long long v1 = ld_byp64(XTsrc + h * 16384 + e + 4);
        char* dst = XS + (e >> 7) * 272 + (e & 127) * 2;
        *reinterpret_cast<unsigned long long*>(dst) = v0;
        *reinterpret_cast<unsigned long long*>(dst + 8) = v1;
      }
      if (h == 0 && tid < 128) sArr[tid] = 1.0f / fmaxf(sqrtf(ld_bypf(SSprev + tid)), 1e-12f);
    }
    __syncthreads();

    #pragma unroll
    for (int mt = 0; mt < 2; ++mt) {
      int R = wv * 32 + mt * 16 + lr;
      bf16x8 a[4];
      #pragma unroll
      for (int ks = 0; ks < 4; ++ks) {
        union { ushort us[8]; bf16x8 v; } u;
        #pragma unroll
        for (int j = 0; j < 8; ++j)
          u.us[j] = *reinterpret_cast<const ushort*>(XS + (ks * 32 + lg * 8 + j) * 272 + R * 2);
        a[ks] = u.v;
      }
      if (h == 0) {
        #pragma unroll
        for (int rr = 0; rr < 4; ++rr) sr[mt][rr] = sArr[wv * 32 + mt * 16 + 4 * lg + rr];
      }
      #pragma unroll
      for (int ks = 0; ks < 4; ++ks) {
        bf16x8 bw = *reinterpret_cast<const bf16x8*>(Wl + (size_t)cG * K + h * 128 + ks * 32 + lg * 8);
        acc1[mt] = __builtin_amdgcn_mfma_f32_16x16x32_bf16(a[ks], bw, acc1[mt], 0, 0, 0);
      }
      #pragma unroll
      for (int ks = 0; ks < 4; ++ks) {
        bf16x8 bw = *reinterpret_cast<const bf16x8*>(Wr + (size_t)cG * K + h * 128 + ks * 32 + lg * 8);
        acc2[mt] = __builtin_amdgcn_mfma_f32_16x16x32_bf16(a[ks], bw, acc2[mt], 0, 0, 0);
      }
    }
  }

  bf16x8 aL[2][4];
  #pragma unroll
  for (int mt = 0; mt < 2; ++mt) {
    int rowL = wv * 32 + mt * 16 + lr;
    ushort iv = f2b(1.0f / (float)(rowL > 1 ? rowL : 1));
    #pragma unroll
    for (int ks = 0; ks < 4; ++ks)
      #pragma unroll
      for (int j = 0; j < 8; ++j) {
        int k = ks * 32 + lg * 8 + j;
        aL[mt][ks][j] = (short)((k < rowL) ? iv : 0);
      }
  }

  #pragma unroll
  for (int mt = 0; mt < 2; ++mt) {
    int m0 = wv * 32 + mt * 16 + lg * 4;
    uint2 pk;
    pk.x = (unsigned)f2b(acc1[mt][0] * sr[mt][0]) | ((unsigned)f2b(acc1[mt][1] * sr[mt][1]) << 16);
    pk.y = (unsigned)f2b(acc1[mt][2] * sr[mt][2]) | ((unsigned)f2b(acc1[mt][3] * sr[mt][3]) << 16);
    *reinterpret_cast<uint2*>(C0T + lr * 256 + ((2 * m0) ^ ((lr & 7) << 4))) = pk;
  }
  __syncthreads();

  {
    bf16x8 bc[4];
    #pragma unroll
    for (int ks = 0; ks < 4; ++ks)
      bc[ks] = *reinterpret_cast<const bf16x8*>(C0T + lr * 256 + ((ks * 64 + lg * 16) ^ ((lr & 7) << 4)));
    float bb = bias[cG];
    #pragma unroll
    for (int mt = 0; mt < 2; ++mt) {
      f32x4 cacc = {0.f, 0.f, 0.f, 0.f};
      #pragma unroll
      for (int ks = 0; ks < 4; ++ks)
        cacc = __builtin_amdgcn_mfma_f32_16x16x32_bf16(aL[mt][ks], bc[ks], cacc, 0, 0, 0);
      int m0 = wv * 32 + mt * 16 + lg * 4;
      float ssq[4];
      if (MODE < 2) {
        float y0 = acc2[mt][0] * sr[mt][0] + bb + cacc[0];
        float y1 = acc2[mt][1] * sr[mt][1] + bb + cacc[1];
        float y2 = acc2[mt][2] * sr[mt][2] + bb + cacc[2];
        float y3 = acc2[mt][3] * sr[mt][3] + bb + cacc[3];
        unsigned lo = (unsigned)f2b(y0) | ((unsigned)f2b(y1) << 16);
        unsigned hi = (unsigned)f2b(y2) | ((unsigned)f2b(y3) << 16);
        st_byp64(&XTdst[(size_t)cG * 128 + m0],
                 (unsigned long long)lo | ((unsigned long long)hi << 32));
        ssq[0] = y0 * y0; ssq[1] = y1 * y1; ssq[2] = y2 * y2; ssq[3] = y3 * y3;
      } else {
        float4 vv;
        vv.x = fmaxf(acc2[mt][0] * sr[mt][0] + bb + cacc[0], 0.f);
        vv.y = fmaxf(acc2[mt][1] * sr[mt][1] + bb + cacc[1], 0.f);
        vv.z = fmaxf(acc2[mt][2] * sr[mt][2] + bb + cacc[2], 0.f);
        vv.w = fmaxf(acc2[mt][3] * sr[mt][3] + bb + cacc[3], 0.f);
        float* yp = &YTdst[(size_t)cG * 128 + m0];
        st_byp64(yp, (unsigned long long)__builtin_bit_cast(unsigned, vv.x) |
                     ((unsigned long long)__builtin_bit_cast(unsigned, vv.y) << 32));
        st_byp64(yp + 2, (unsigned long long)__builtin_bit_cast(unsigned, vv.z) |
                         ((unsigned long long)__builtin_bit_cast(unsigned, vv.w) << 32));
        ssq[0] = vv.x * vv.x; ssq[1] = vv.y * vv.y; ssq[2] = vv.z * vv.z; ssq[3] = vv.w * vv.w;
      }
      #pragma unroll
      for (int rr = 0; rr < 4; ++rr) {
        float ss = ssq[rr];
        ss += __shfl_xor(ss, 1); ss += __shfl_xor(ss, 2);
        ss += __shfl_xor(ss, 4); ss += __shfl_xor(ss, 8);
        if (lr == 0) atomicAdd(&SScur[m0 + rr], ss);
      }
    }
  }
}

// ---------------- sage (barrier-free, per-wave 12K region) ----------------
__device__ inline void sage_stage(const float* __restrict__ flows, int blk,
                                  char* W, float* sArr, int wv, int lane) {
  int r2 = lane >> 5;
  int c4 = lane & 31;
  #pragma unroll
  for (int it = 0; it < 8; ++it) {
    int rl0 = it * 2;
    const float4 v = *reinterpret_cast<const float4*>(
        flows + ((size_t)blk * 64 + wv * 16 + rl0) * 128 + lane * 4);
    int rl = rl0 + r2;
    float ss = v.x * v.x + v.y * v.y + v.z * v.z + v.w * v.w;
    ss += __shfl_xor(ss, 16); ss += __shfl_xor(ss, 8);
    ss += __shfl_xor(ss, 4);  ss += __shfl_xor(ss, 2); ss += __shfl_xor(ss, 1);
    uint2 pk;
    pk.x = (unsigned)f2b(v.x) | ((unsigned)f2b(v.y) << 16);
    pk.y = (unsigned)f2b(v.z) | ((unsigned)f2b(v.w) << 16);
    *reinterpret_cast<uint2*>(W + rl * 256 + ((c4 * 8) ^ ((rl & 7) << 4))) = pk;
    if (c4 == 0) sArr[wv * 16 + rl] = rsqrtf(ss * (1.0f / 128.0f));
  }
}

template <int N, int DSTC>
__device__ inline void sage_l128(const char* src, char* dstW,
                                 const float* sP, float* sN,
                                 const ushort* __restrict__ Wrp,
                                 const float* __restrict__ bias,
                                 int wv, int lr, int lg, int l64) {
  bf16x8 a[4];
  float sr[4];
  #pragma unroll
  for (int ks = 0; ks < 4; ++ks)
    a[ks] = *reinterpret_cast<const bf16x8*>(src + lr * 256 + ((ks * 64 + lg * 16) ^ ((lr & 7) << 4)));
  #pragma unroll
  for (int rr = 0; rr < 4; ++rr) sr[rr] = sP[wv * 16 + 4 * lg + rr];
  float ssq[4] = {0.f, 0.f, 0.f, 0.f};
  #pragma unroll
  for (int nt = 0; nt < N / 16; ++nt) {
    int col = nt * 16 + lr;
    bf16x8 b[4];
    #pragma unroll
    for (int ks = 0; ks < 4; ++ks)
      b[ks] = *reinterpret_cast<const bf16x8*>(Wrp + (((size_t)nt * 4 + ks) * 64 + l64) * 8);
    f32x4 acc = {0.f, 0.f, 0.f, 0.f};
    #pragma unroll
    for (int ks = 0; ks < 4; ++ks)
      acc = __builtin_amdgcn_mfma_f32_16x16x32_bf16(a[ks], b[ks], acc, 0, 0, 0);
    float bb = bias[col];
    #pragma unroll
    for (int rr = 0; rr < 4; ++rr) {
      int rl = 4 * lg + rr;
      float y = acc[rr] * sr[rr] + bb;
      int rowbase = DSTC ? cAddrRow(rl) : rl * 256;
      *reinterpret_cast<ushort*>(dstW + rowbase + ((col * 2) ^ ((rl & 7) << 4))) = f2b(y);
      ssq[rr] += y * y;
    }
  }
  #pragma unroll
  for (int rr = 0; rr < 4; ++rr) {
    float ss = ssq[rr];
    ss += __shfl_xor(ss, 1); ss += __shfl_xor(ss, 2);
    ss += __shfl_xor(ss, 4); ss += __shfl_xor(ss, 8);
    if (lr == 0) sN[wv * 16 + 4 * lg + rr] = 1.0f / fmaxf(sqrtf(ss), 1e-12f);
  }
}

__device__ inline void sage_l3(const char* W, char* dstD,
                               const float* sP, float* sN,
                               const ushort* __restrict__ Wrp,
                               const float* __restrict__ bias,
                               int wv, int lr, int lg, int l64) {
  bf16x8 a[8];
  float sr[4];
  #pragma unroll
  for (int ks = 0; ks < 8; ++ks)
    a[ks] = *reinterpret_cast<const bf16x8*>(W + cAddrRow(lr) + ((ks * 64 + lg * 16) ^ ((lr & 7) << 4)));
  #pragma unroll
  for (int rr = 0; rr < 4; ++rr) sr[rr] = sP[wv * 16 + 4 * lg + rr];
  float ssq[4] = {0.f, 0.f, 0.f, 0.f};
  #pragma unroll
  for (int nt = 0; nt < 8; ++nt) {
    int col = nt * 16 + lr;
    f32x4 acc = {0.f, 0.f, 0.f, 0.f};
    #pragma unroll
    for (int ks = 0; ks < 8; ++ks) {
      bf16x8 b = *reinterpret_cast<const bf16x8*>(Wrp + (((size_t)nt * 8 + ks) * 64 + l64) * 8);
      acc = __builtin_amdgcn_mfma_f32_16x16x32_bf16(a[ks], b, acc, 0, 0, 0);
    }
    float bb = bias[col];
    #pragma unroll
    for (int rr = 0; rr < 4; ++rr) {
      int rl = 4 * lg + rr;
      float y = acc[rr] * sr[rr] + bb;
      *reinterpret_cast<ushort*>(dstD + rl * 256 + ((col * 2) ^ ((rl & 7) << 4))) = f2b(y);
      ssq[rr] += y * y;
    }
  }
  #pragma unroll
  for (int rr = 0; rr < 4; ++rr) {
    float ss = ssq[rr];
    ss += __shfl_xor(ss, 1); ss += __shfl_xor(ss, 2);
    ss += __shfl_xor(ss, 4); ss += __shfl_xor(ss, 8);
    if (lr == 0) sN[wv * 16 + 4 * lg + rr] = 1.0f / fmaxf(sqrtf(ss), 1e-12f);
  }
}

__device__ inline void sage_l4(const char* src, const float* sP,
                               const ushort* __restrict__ Wrp,
                               const float* __restrict__ bias,
                               int wv, int lr, int lg, int l64,
                               ushort* __restrict__ Fg, int blk) {
  bf16x8 a[4];
  float sr[4];
  #pragma unroll
  for (int ks = 0; ks < 4; ++ks)
    a[ks] = *reinterpret_cast<const bf16x8*>(src + lr * 256 + ((ks * 64 + lg * 16) ^ ((lr & 7) << 4)));
  #pragma unroll
  for (int rr = 0; rr < 4; ++rr) sr[rr] = sP[wv * 16 + 4 * lg + rr];
  float yreg[8][4];
  float ssq[4] = {0.f, 0.f, 0.f, 0.f};
  #pragma unroll
  for (int nt = 0; nt < 8; ++nt) {
    int col = nt * 16 + lr;
    bf16x8 b[4];
    #pragma unroll
    for (int ks = 0; ks < 4; ++ks)
      b[ks] = *reinterpret_cast<const bf16x8*>(Wrp + (((size_t)nt * 4 + ks) * 64 + l64) * 8);
    f32x4 acc = {0.f, 0.f, 0.f, 0.f};
    #pragma unroll
    for (int ks = 0; ks < 4; ++ks)
      acc = __builtin_amdgcn_mfma_f32_16x16x32_bf16(a[ks], b[ks], acc, 0, 0, 0);
    float bb = bias[col];
    #pragma unroll
    for (int rr = 0; rr < 4; ++rr) {
      float y = acc[rr] * sr[rr] + bb;
      yreg[nt][rr] = y;
      float v = fmaxf(y, 0.f);
      ssq[rr] += v * v;
    }
  }
  float sc[4];
  #pragma unroll
  for (int rr = 0; rr < 4; ++rr) {
    float ss = ssq[rr];
    ss += __shfl_xor(ss, 1); ss += __shfl_xor(ss, 2);
    ss += __shfl_xor(ss, 4); ss += __shfl_xor(ss, 8);
    sc[rr] = sqrtf(128.0f / fmaxf(ss, 1e-20f));
  }
  #pragma unroll
  for (int nt = 0; nt < 8; ++nt)
    #pragma unroll
    for (int rr = 0; rr < 4; ++rr) {
      int row = wv * 16 + 4 * lg + rr;
      Fg[((size_t)blk * 64 + row) * 128 + nt * 16 + lr] = f2b(fmaxf(yreg[nt][rr], 0.f) * sc[rr]);
    }
}

// ---------------- mega3: chain (0..15) + prep_mb (16..23) + sage (24..533) ----------------
__global__ __launch_bounds__(256, 2) void mega3_k(
    const float* __restrict__ flows,
    const float* __restrict__ qsa, const float* __restrict__ ksa,
    const ushort* __restrict__ WL, const ushort* __restrict__ WR,
    const ushort* __restrict__ WRp,
    const float* __restrict__ bl1, const float* __restrict__ bl2,
    const float* __restrict__ bl3, const float* __restrict__ bl4,
    ushort* __restrict__ Fg, ushort* __restrict__ MBT,
    ushort* __restrict__ XT1, ushort* __restrict__ XT2, ushort* __restrict__ XT3,
    float* __restrict__ YT4, float* __restrict__ SS, unsigned* __restrict__ CTR) {
  __shared__ char L[49664];
  const int bid = blockIdx.x;
  const int tid = threadIdx.x;
  const int lane = tid & 63, wv = tid >> 6, lr = lane & 15, lg = lane >> 4;

  if (bid < 16) {
    char* XS = L;
    char* C0T = L + 34816;
    float* sArr = (float*)(L + 38912);
    int cbid = bid;
    if (cbid < 8) {
      chain_dev<128, 128, 0>(XS, C0T, sArr, flows, nullptr, nullptr,
                             WL + 0, WR + 0, bl1, XT1, nullptr, SS + 0, cbid);
      ctr_signal(&CTR[0]);
    }
    ctr_wait(&CTR[0], 8);
    chain_dev<128, 256, 1>(XS, C0T, sArr, nullptr, XT1, SS + 0,
                           WL + 16384, WR + 16384, bl2, XT2, nullptr, SS + 128, cbid);
    ctr_signal(&CTR[1]);
    ctr_wait(&CTR[1], 16);
    if (cbid < 8) {
      chain_dev<256, 128, 1>(XS, C0T, sArr, nullptr, XT2, SS + 128,
                             WL + 49152, WR + 49152, bl3, XT3, nullptr, SS + 256, cbid);
      ctr_signal(&CTR[2]);
    }
    ctr_wait(&CTR[2], 8);
    if (cbid < 8) {
      chain_dev<128, 128, 2>(XS, C0T, sArr, nullptr, XT3, SS + 256,
                             WL + 81920, WR + 81920, bl4, nullptr, YT4, SS + 384, cbid);
      ctr_signal(&CTR[3]);
    }
    ctr_wait(&CTR[3], 8);
    if (cbid < 8) {
      int t = cbid * 256 + tid;
      int r = t >> 4, cs = t & 15;
      float sc = sqrtf(128.0f / fmaxf(ld_bypf(&SS[384 + r]), 1e-20f));
      ushort tmp[8];
      #pragma unroll
      for (int j = 0; j < 8; ++j) {
        int c = cs * 8 + j;
        tmp[j] = f2b(ld_bypf(&YT4[(size_t)c * 128 + r]) * sc);
      }
      *reinterpret_cast<uint4*>(&Fg[(size_t)r * 128 + cs * 8]) = *reinterpret_cast<uint4*>(tmp);
    }
    return;
  }

  if (bid < 24) {
    char* QT = L;
    int w = bid - 16;
    const float* qw = qsa + (size_t)w * 16384;
    const float* kw = ksa + (size_t)w * 16384;
    for (int e = tid; e < 16384; e += 256) {
      int op = e >> 7, c = e & 127;
      int off = c * 256 + ((op * 2) ^ ((c & 7) << 4));
      *reinterpret_cast<ushort*>(QT + off) = f2b(qw[e]);
    }
    __syncthreads();
    #pragma unroll
    for (int rt = 0; rt < 2; ++rt) {
      int e = wv * 32 + rt * 16 + lr;
      bf16x8 a[4];
      #pragma unroll
      for (int ks = 0; ks < 4; ++ks) {
        union { ushort us[8]; bf16x8 v; } u;
        #pragma unroll
        for (int j = 0; j < 8; ++j)
          u.us[j] = f2b(kw[(size_t)(ks * 32 + lg * 8 + j) * 128 + e]);
        a[ks] = u.v;
      }
      #pragma unroll
      for (int ct = 0; ct < 8; ++ct) {
        int d = ct * 16 + lr;
        bf16x8 bq[4];
        #pragma unroll
        for (int ks = 0; ks < 4; ++ks)
          bq[ks] = *reinterpret_cast<const bf16x8*>(QT + d * 256 + ((ks * 64 + lg * 16) ^ ((d & 7) << 4)));
        f32x4 acc = {0.f, 0.f, 0.f, 0.f};
        #pragma unroll
        for (int ks = 0; ks < 4; ++ks)
          acc = __builtin_amdgcn_mfma_f32_16x16x32_bf16(a[ks], bq[ks], acc, 0, 0, 0);
        uint2 pk;
        pk.x = (unsigned)f2b(acc[0]) | ((unsigned)f2b(acc[1]) << 16);
        pk.y = (unsigned)f2b(acc[2]) | ((unsigned)f2b(acc[3]) << 16);
        size_t base = ((((size_t)ct * 8 + w) * 4 + wv) * 64 +
                       (size_t)(((rt * 2 + (lg >> 1)) & 3) * 16 + lr)) * 8 + (lg & 1) * 4;
        *reinterpret_cast<uint2*>(&MBT[base]) = pk;
      }
    }
    return;
  }

  // ---- sage path ----
  char* W = L + wv * 12288;
  float* sA = (float*)(L + 49152);
  float* sB = (float*)(L + 49408);
  const int l64 = lane;
  int blk = bid - 24 + 2;
  sage_stage(flows, blk, W, sA, wv, lane);
  asm volatile("" ::: "memory");
  sage_l128<128, 0>(W, W + 4096, sA, sB, WRp + 0,     bl1, wv, lr, lg, l64);
  asm volatile("" ::: "memory");
  sage_l128<256, 1>(W + 4096, W, sB, sA, WRp + 16384, bl2, wv, lr, lg, l64);
  asm volatile("" ::: "memory");
  sage_l3(W, W + 4096, sA, sB, WRp + 49152, bl3, wv, lr, lg, l64);
  asm volatile("" ::: "memory");
  sage_l4(W + 4096, sB, WRp + 81920, bl4, wv, lr, lg, l64, Fg, blk);
}

// ---------------- attn v6: 512 blocks x 512 thr, dbuf RT, coalesced SBp/MBT ----------------
__global__ __launch_bounds__(512, 4) void attn_fused(
    const ushort* __restrict__ F, const ushort* __restrict__ MBT,
    const ushort* __restrict__ SBp, float* __restrict__ Out) {
  __shared__ char FT[32768];
  __shared__ char RTb[32768];

  const int bq = blockIdx.x;
  const int b = bq >> 1, ph = bq & 1;
  const int tid = threadIdx.x;
  const int l = tid & 63, wv = tid >> 6;
  const int lr = l & 15, lg = l >> 4;

  const ushort* Fb = F + (size_t)b * 16384;

  #pragma unroll
  for (int it = 0; it < 4; ++it) {
    int idx = tid + it * 512;
    int m = idx >> 4, eg = idx & 15;
    uint4 v = *reinterpret_cast<const uint4*>(Fb + m * 128 + eg * 8);
    const ushort* pv = reinterpret_cast<const ushort*>(&v);
    #pragma unroll
    for (int j = 0; j < 8; ++j) {
      int e = eg * 8 + j;
      *reinterpret_cast<ushort*>(FT + e * 256 + ((m * 2) ^ ftswz(e))) = pv[j];
    }
  }

  bf16x8 fa[4];
  {
    int n = wv * 16 + lr;
    #pragma unroll
    for (int ks = 0; ks < 4; ++ks)
      fa[ks] = *reinterpret_cast<const bf16x8*>(Fb + n * 128 + ks * 32 + lg * 8);
  }
  __syncthreads();

  bf16x8 af[4];
  {
    int e = wv * 16 + lr;
    #pragma unroll
    for (int ks = 0; ks < 4; ++ks)
      af[ks] = *reinterpret_cast<const bf16x8*>(
          FT + e * 256 + ((ks * 64 + lg * 16) ^ ftswz(e)));
  }

  f32x4 zacc[4];
  #pragma unroll
  for (int pt = 0; pt < 4; ++pt) zacc[pt] = f32x4{0.f, 0.f, 0.f, 0.f};

  const int eb0 = 2 * (wv * 16 + lg * 4);

  auto Rphase = [&](int w, char* RT) {
    #pragma unroll
    for (int pt = 0; pt < 4; ++pt) {
      int p = pt * 16 + lr;
      bf16x8 bs[4];
      #pragma unroll
      for (int ks = 0; ks < 4; ++ks)
        bs[ks] = *reinterpret_cast<const bf16x8*>(
            SBp + ((((size_t)(w * 2 + ph) * 4 + pt) * 4 + ks) * 64 + l) * 8);
      f32x4 rr = {0.f, 0.f, 0.f, 0.f};
      #pragma unroll
      for (int ks = 0; ks < 4; ++ks)
        rr = __builtin_amdgcn_mfma_f32_16x16x32_bf16(af[ks], bs[ks], rr, 0, 0, 0);
      uint2 pk;
      pk.x = (unsigned)f2b(rr[0]) | ((unsigned)f2b(rr[1]) << 16);
      pk.y = (unsigned)f2b(rr[2]) | ((unsigned)f2b(rr[3]) << 16);
      *reinterpret_cast<uint2*>(RT + p * 256 + (eb0 ^ ((p & 7) << 4))) = pk;
    }
  };
  auto Zphase = [&](int w, const char* RT) {
    bf16x8 mf[4];
    #pragma unroll
    for (int ks = 0; ks < 4; ++ks)
      mf[ks] = *reinterpret_cast<const bf16x8*>(
          MBT + ((((size_t)wv * 8 + w) * 4 + ks) * 64 + l) * 8);
    #pragma unroll
    for (int pt = 0; pt < 4; ++pt) {
      int p = pt * 16 + lr;
      bf16x8 bg[4];
      #pragma unroll
      for (int ks = 0; ks < 4; ++ks)
        bg[ks] = *reinterpret_cast<const bf16x8*>(
            RT + p * 256 + ((ks * 64 + lg * 16) ^ ((p & 7) << 4)));
      #pragma unroll
      for (int ks = 0; ks < 4; ++ks)
        zacc[pt] = __builtin_amdgcn_mfma_f32_16x16x32_bf16(mf[ks], bg[ks], zacc[pt], 0, 0, 0);
    }
  };

  Rphase(0, RTb);
  __syncthreads();
  #pragma unroll
  for (int w = 0; w < 7; ++w) {
    Zphase(w, RTb + (w & 1) * 16384);
    Rphase(w + 1, RTb + ((w + 1) & 1) * 16384);
    __syncthreads();
  }
  Zphase(7, RTb + 16384);
  #pragma unroll
  for (int pt = 0; pt < 4; ++pt) {
    int p = pt * 16 + lr;
    uint2 pk;
    pk.x = (unsigned)f2b(zacc[pt][0]) | ((unsigned)f2b(zacc[pt][1]) << 16);
    pk.y = (unsigned)f2b(zacc[pt][2]) | ((unsigned)f2b(zacc[pt][3]) << 16);
    *reinterpret_cast<uint2*>(RTb + p * 256 + (eb0 ^ ((p & 7) << 4))) = pk;
  }
  __syncthreads();

  const float inv_scale = 0.08838834764831845f;
  float* ob = Out + (size_t)b * 16384 + ph * 64;
  #pragma unroll
  for (int pt = 0; pt < 4; ++pt) {
    int p = pt * 16 + lr;
    bf16x8 bz[4];
    #pragma unroll
    for (int ks = 0; ks < 4; ++ks)
      bz[ks] = *reinterpret_cast<const bf16x8*>(
          RTb + p * 256 + ((ks * 64 + lg * 16) ^ ((p & 7) << 4)));
    f32x4 oa = {0.f, 0.f, 0.f, 0.f};
    #pragma unroll
    for (int ks = 0; ks < 4; ++ks)
      oa = __builtin_amdgcn_mfma_f32_16x16x32_bf16(fa[ks], bz[ks], oa, 0, 0, 0);
    int n0 = wv * 16 + lg * 4;
    #pragma unroll
    for (int r = 0; r < 4; ++r)
      ob[(size_t)(n0 + r) * 128 + p] = oa[r] * inv_scale;
  }
}

extern "C" void kernel_launch(void* const* d_in, const int* in_sizes, int n_in,
                              void* d_out, int out_size, void* d_ws, size_t ws_size,
                              hipStream_t stream) {
  const float* flows = (const float*)d_in[0];
  const float* g1_wl = (const float*)d_in[10];
  const float* g1_bl = (const float*)d_in[11];
  const float* g1_wr = (const float*)d_in[12];
  const float* g2_wl = (const float*)d_in[13];
  const float* g2_bl = (const float*)d_in[14];
  const float* g2_wr = (const float*)d_in[15];
  const float* g3_wl = (const float*)d_in[16];
  const float* g3_bl = (const float*)d_in[17];
  const float* g3_wr = (const float*)d_in[18];
  const float* g4_wl = (const float*)d_in[19];
  const float* g4_bl = (const float*)d_in[20];
  const float* g4_wr = (const float*)d_in[21];
  const float* qsa   = (const float*)d_in[24];
  const float* ksa   = (const float*)d_in[25];
  const float* s2w   = (const float*)d_in[27];
  float* out = (float*)d_out;
  char* wsb  = (char*)d_ws;

  // workspace layout (bytes)
  ushort* FB16 = (ushort*)(wsb);                 // 32768*128 bf16 = 8388608
  ushort* SBp  = (ushort*)(wsb + 8388608);       // 131072 bf16 (permuted)
  ushort* WL   = (ushort*)(wsb + 8650752);       // 98304 bf16
  ushort* WR   = (ushort*)(wsb + 8847360);       // 98304 bf16
  ushort* MBT  = (ushort*)(wsb + 9043968);       // 131072 bf16 (permuted)
  ushort* XT1  = (ushort*)(wsb + 9306112);       // 128*128 bf16
  ushort* XT2  = (ushort*)(wsb + 9338880);       // 256*128 bf16
  ushort* XT3  = (ushort*)(wsb + 9404416);       // 128*128 bf16
  float*  YT4  = (float*)(wsb + 9437184);        // 128*128 f32
  float*  SS   = (float*)(wsb + 9502720);        // 512 f32
  ushort* WRp  = (ushort*)(wsb + 9504768);       // 98304 bf16 (permuted)
  unsigned* CTR = (unsigned*)(wsb + 9701376);    // 8 u32 chain layer counters

  prep_all_k<<<896, 256, 0, stream>>>(s2w,
                                      g1_wl, g2_wl, g3_wl, g4_wl,
                                      g1_wr, g2_wr, g3_wr, g4_wr,
                                      SBp, WL, WR, WRp, SS, CTR);
  mega3_k<<<534, 256, 0, stream>>>(flows, qsa, ksa, WL, WR, WRp,
                                   g1_bl, g2_bl, g3_bl, g4_bl,
                                   FB16, MBT, XT1, XT2, XT3, YT4, SS, CTR);
  attn_fused<<<512, 512, 0, stream>>>(FB16, MBT, SBp, out);
}